// Round 12
// baseline (248.269 us; speedup 1.0000x reference)
//
#include <hip/hip_runtime.h>
#include <hip/hip_bf16.h>

#define H 128
#define VOCAB 100000
#define B_SESS 1024
#define NODES 32
#define ITEMS 16
#define PADLEN 8
#define NCHUNK 32

typedef short short8 __attribute__((ext_vector_type(8)));
typedef float f32x16 __attribute__((ext_vector_type(16)));
typedef float f32x4 __attribute__((ext_vector_type(4)));

static __device__ __forceinline__ short f2bf(float x) {
    unsigned u = __builtin_bit_cast(unsigned, x);
    u += 0x7fffu + ((u >> 16) & 1u);   // round-to-nearest-even (no NaNs in this data)
    return (short)(u >> 16);
}

// ---------------------------------------------------------------------------
// Kernel 0: transpose weights once so k_session weight reads are coalesced.
// ---------------------------------------------------------------------------
__global__ __launch_bounds__(256) void k_transpose(
    const float* __restrict__ W1, const float* __restrict__ W2,
    const float* __restrict__ W3,
    float* __restrict__ W1t, float* __restrict__ W2t, float* __restrict__ W3t)
{
    const int idx = blockIdx.x * 256 + threadIdx.x;   // 0..16383
    const int k = idx >> 7, j = idx & 127;
    W1t[idx] = W1[j * H + k];
    W2t[idx] = W2[j * H + k];
    W3t[k * H + j]       = W3[j * 2 * H + k];
    W3t[(k + H) * H + j] = W3[j * 2 * H + k + H];
}

// ---------------------------------------------------------------------------
// Kernel 1: per-session gather-mean + gate/alpha/s_g/s_h/y_hat. (R5 version)
// ---------------------------------------------------------------------------
__global__ __launch_bounds__(H) void k_session(
    const float* __restrict__ node_emb,
    const int* __restrict__ sequence,
    const int* __restrict__ itemset_len,
    const float* __restrict__ W1t, const float* __restrict__ W1_b,
    const float* __restrict__ W2t, const float* __restrict__ W2_b,
    const float* __restrict__ q_w,  const float* __restrict__ q_b,
    const float* __restrict__ W3t, const float* __restrict__ W3_b,
    const float* __restrict__ emb_weight, const int* __restrict__ cue,
    float* __restrict__ y_hat, short* __restrict__ packA)
{
    __shared__ float it[ITEMS][H];        // 8 KB
    __shared__ float contrib[ITEMS][H];   // 8 KB
    __shared__ float red[ITEMS][8];
    __shared__ float alphas[ITEMS];
    __shared__ float sg[H];
    __shared__ float wred[2];

    const int b = blockIdx.x;
    const int j = threadIdx.x;            // 0..127
    const int nbase = b * NODES;

    // --- itemset embeddings: masked gather-mean over this session's 32 nodes
#pragma unroll
    for (int t = 0; t < ITEMS; ++t) {
        const int tg = b * ITEMS + t;
        float acc = 0.f;
#pragma unroll
        for (int p = 0; p < PADLEN; ++p) {
            int s = sequence[tg * PADLEN + p];
            if (s < NODES) acc += node_emb[(nbase + s) * H + j];
        }
        it[t][j] = acc / (float)itemset_len[tg];
    }
    __syncthreads();

    // pre_j = W1_b[j] + W2_b[j] + dot(W1[j,:], v_n)   (v_n = it[15])
    float pre = W1_b[j] + W2_b[j];
#pragma unroll 4
    for (int k = 0; k < H; k += 4) {
        float4 v = *(const float4*)&it[ITEMS - 1][k];
        pre += W1t[(k + 0) * H + j] * v.x + W1t[(k + 1) * H + j] * v.y
             + W1t[(k + 2) * H + j] * v.z + W1t[(k + 3) * H + j] * v.w;
    }

    // h2[t] = dot(W2[j,:], it[t])  for all 16 t, streaming W2t rows (coalesced)
    float h2[ITEMS];
#pragma unroll
    for (int t = 0; t < ITEMS; ++t) h2[t] = 0.f;
    for (int k = 0; k < H; k += 4) {
        float w0 = W2t[(k + 0) * H + j];
        float w1 = W2t[(k + 1) * H + j];
        float w2 = W2t[(k + 2) * H + j];
        float w3 = W2t[(k + 3) * H + j];
#pragma unroll
        for (int t = 0; t < ITEMS; ++t) {
            float4 v = *(const float4*)&it[t][k];
            h2[t] += w0 * v.x + w1 * v.y + w2 * v.z + w3 * v.w;
        }
    }

    // contrib[t][j] = q_w[j] * sigmoid(pre + h2[t])
    const float qwj = q_w[j];
#pragma unroll
    for (int t = 0; t < ITEMS; ++t) {
        float g = 1.f / (1.f + __expf(-(pre + h2[t])));
        contrib[t][j] = qwj * g;
    }
    __syncthreads();

    // block reduce contrib rows -> alphas[t]
    {
        int t = j >> 3, part = j & 7;
        float s = 0.f;
#pragma unroll
        for (int u = 0; u < 16; ++u) s += contrib[t][part * 16 + u];
        red[t][part] = s;
    }
    __syncthreads();
    if (j < ITEMS) {
        float s = q_b[0];
#pragma unroll
        for (int u = 0; u < 8; ++u) s += red[j][u];
        alphas[j] = s;
    }
    __syncthreads();

    // s_g[j] = sum_t alphas[t] * it[t][j]
    float sgj = 0.f;
#pragma unroll
    for (int t = 0; t < ITEMS; ++t) sgj += alphas[t] * it[t][j];
    sg[j] = sgj;
    __syncthreads();

    // s_h[j] = W3_b[j] + dot(W3[j,0:128], v_n) + dot(W3[j,128:256], s_g)
    float sh = W3_b[j];
#pragma unroll 4
    for (int k = 0; k < H; k += 4) {
        float4 v = *(const float4*)&it[ITEMS - 1][k];
        sh += W3t[(k + 0) * H + j] * v.x + W3t[(k + 1) * H + j] * v.y
            + W3t[(k + 2) * H + j] * v.z + W3t[(k + 3) * H + j] * v.w;
    }
#pragma unroll 4
    for (int k = 0; k < H; k += 4) {
        float4 v = *(const float4*)&sg[k];
        sh += W3t[(H + k + 0) * H + j] * v.x + W3t[(H + k + 1) * H + j] * v.y
            + W3t[(H + k + 2) * H + j] * v.z + W3t[(H + k + 3) * H + j] * v.w;
    }

    // write s_h (bf16) in MFMA-fragment-packed layout: k index == j
    {
        const int c = b >> 5, cl = b & 31;
        const int s = j >> 4, hi = (j >> 3) & 1, i = j & 7;
        packA[c * 4096 + s * 512 + hi * 256 + cl * 8 + i] = f2bf(sh);
    }

    // y_hat[b] = dot(s_h, emb_weight[cue[b]])  — full f32
    float prod = sh * emb_weight[(long)cue[b] * H + j];
#pragma unroll
    for (int off = 32; off > 0; off >>= 1) prod += __shfl_down(prod, off);
    if ((j & 63) == 0) wred[j >> 6] = prod;
    __syncthreads();
    if (j == 0) y_hat[b] = wred[0] + wred[1];
}

// ---------------------------------------------------------------------------
// Kernel 2 (PROBE BUILD): R7 geometry exactly, but the M-loop executes TWICE
// (identical stores both passes -> output unchanged). Doubles the dispatch
// duration past the ~232us harness fills so k_scores' own counters appear in
// the top-5 table: dur/2 = M-loop cost; WRITE_SIZE tests write amplification;
// FETCH_SIZE tests NT-load read amplification on the stride-512B emb gather.
// ---------------------------------------------------------------------------
__global__ __launch_bounds__(256, 4) void k_scores(
    const float* __restrict__ emb_weight,
    const short* __restrict__ packA,
    float* __restrict__ scores)
{
    // m204 bijective swizzle, nwg = 782, 8 XCDs (round-robin dispatch)
    const int nwg = 782;
    const int xcd = blockIdx.x & 7;
    const int idx = blockIdx.x >> 3;
    const int q = nwg >> 3, r = nwg & 7;          // 97, 6
    const int bid = (xcd < r) ? (xcd * (q + 1) + idx)
                              : (r * (q + 1) + (xcd - r) * q + idx);

    const int wave = threadIdx.x >> 6;
    const int lane = threadIdx.x & 63;
    const int hi = lane >> 5;             // k-group
    const int cl = lane & 31;             // col within tile / row within A
    const int col = bid * 128 + wave * 32 + cl;
    const bool valid = col < VOCAB;       // V%32==0 -> wave-uniform

    // B fragment: lane holds emb[col][s*16 + hi*8 + i], i=0..7, for s=0..7
    short8 bfrag[8];
    if (valid) {
        const float* row = emb_weight + (long)col * H;
#pragma unroll
        for (int s = 0; s < 8; ++s) {
            const f32x4* p = (const f32x4*)(row + s * 16 + hi * 8);
            f32x4 x = __builtin_nontemporal_load(p);
            f32x4 y = __builtin_nontemporal_load(p + 1);
            short8 f;
            f[0] = f2bf(x[0]); f[1] = f2bf(x[1]); f[2] = f2bf(x[2]); f[3] = f2bf(x[3]);
            f[4] = f2bf(y[0]); f[5] = f2bf(y[1]); f[6] = f2bf(y[2]); f[7] = f2bf(y[3]);
            bfrag[s] = f;
        }
    } else {
#pragma unroll
        for (int s = 0; s < 8; ++s) {
            short8 z;
#pragma unroll
            for (int i = 0; i < 8; ++i) z[i] = 0;
            bfrag[s] = z;
        }
    }

#pragma clang loop unroll(disable)
    for (int rep = 0; rep < 2; ++rep) {
        for (int c = 0; c < NCHUNK; ++c) {
            const short* ap = packA + c * 4096 + hi * 256 + cl * 8;
            short8 a[8];
#pragma unroll
            for (int s = 0; s < 8; ++s) a[s] = *(const short8*)(ap + s * 512);
            f32x16 acc;
#pragma unroll
            for (int r2 = 0; r2 < 16; ++r2) acc[r2] = 0.f;
#pragma unroll
            for (int s = 0; s < 8; ++s)
                acc = __builtin_amdgcn_mfma_f32_32x32x16_bf16(a[s], bfrag[s], acc, 0, 0, 0);
            if (valid) {
                const int M0 = c * 32;
#pragma unroll
                for (int r2 = 0; r2 < 16; ++r2) {
                    int rowm = (r2 & 3) + 8 * (r2 >> 2) + 4 * hi;
                    __builtin_nontemporal_store(acc[r2],
                        &scores[(long)(M0 + rowm) * VOCAB + col]);
                }
            }
        }
    }
}

// ---------------------------------------------------------------------------
extern "C" void kernel_launch(void* const* d_in, const int* in_sizes, int n_in,
                              void* d_out, int out_size, void* d_ws, size_t ws_size,
                              hipStream_t stream) {
    const float* node_emb   = (const float*)d_in[0];
    const float* emb_w      = (const float*)d_in[1];
    const float* W1_w       = (const float*)d_in[2];
    const float* W1_b       = (const float*)d_in[3];
    const float* W2_w       = (const float*)d_in[4];
    const float* W2_b       = (const float*)d_in[5];
    const float* q_w        = (const float*)d_in[6];
    const float* q_b        = (const float*)d_in[7];
    const float* W3_w       = (const float*)d_in[8];
    const float* W3_b       = (const float*)d_in[9];
    // d_in[10] batch (= repeat(arange(B),32)), d_in[13] sequence_len (=16): structure hardcoded
    const int* sequence     = (const int*)d_in[11];
    const int* itemset_len  = (const int*)d_in[12];
    const int* cue          = (const int*)d_in[14];

    float* out    = (float*)d_out;
    float* y_hat  = out;                   // [B]
    float* scores = out + B_SESS;          // [B][V]

    short* packA = (short*)d_ws;                            // 256 KB
    float* W1t   = (float*)((char*)d_ws + (256 << 10));     // 64 KB
    float* W2t   = W1t + H * H;                             // 64 KB
    float* W3t   = W2t + H * H;                             // 128 KB

    k_transpose<<<64, 256, 0, stream>>>(W1_w, W2_w, W3_w, W1t, W2t, W3t);
    k_session<<<B_SESS, H, 0, stream>>>(node_emb, sequence, itemset_len,
                                        W1t, W1_b, W2t, W2_b,
                                        q_w, q_b, W3t, W3_b, emb_w, cue,
                                        y_hat, packA);
    const int nblk = (VOCAB + 127) / 128;  // 782
    k_scores<<<nblk, 256, 0, stream>>>(emb_w, packA, scores);
}

// Round 13
// 142.473 us; speedup vs baseline: 1.7426x; 1.7426x over previous
//
#include <hip/hip_runtime.h>
#include <hip/hip_bf16.h>

#define H 128
#define VOCAB 100000
#define B_SESS 1024
#define NODES 32
#define ITEMS 16
#define PADLEN 8
#define NCHUNK 32

typedef short short8 __attribute__((ext_vector_type(8)));
typedef float f32x16 __attribute__((ext_vector_type(16)));
typedef float f32x4 __attribute__((ext_vector_type(4)));

static __device__ __forceinline__ short f2bf(float x) {
    unsigned u = __builtin_bit_cast(unsigned, x);
    u += 0x7fffu + ((u >> 16) & 1u);   // round-to-nearest-even (no NaNs in this data)
    return (short)(u >> 16);
}

// ---------------------------------------------------------------------------
// Kernel 0: transpose weights once so k_session weight reads are coalesced.
// ---------------------------------------------------------------------------
__global__ __launch_bounds__(256) void k_transpose(
    const float* __restrict__ W1, const float* __restrict__ W2,
    const float* __restrict__ W3,
    float* __restrict__ W1t, float* __restrict__ W2t, float* __restrict__ W3t)
{
    const int idx = blockIdx.x * 256 + threadIdx.x;   // 0..16383
    const int k = idx >> 7, j = idx & 127;
    W1t[idx] = W1[j * H + k];
    W2t[idx] = W2[j * H + k];
    W3t[k * H + j]       = W3[j * 2 * H + k];
    W3t[(k + H) * H + j] = W3[j * 2 * H + k + H];
}

// ---------------------------------------------------------------------------
// Kernel 1: per-session gather-mean + gate/alpha/s_g/s_h/y_hat. (R5 version)
// ---------------------------------------------------------------------------
__global__ __launch_bounds__(H) void k_session(
    const float* __restrict__ node_emb,
    const int* __restrict__ sequence,
    const int* __restrict__ itemset_len,
    const float* __restrict__ W1t, const float* __restrict__ W1_b,
    const float* __restrict__ W2t, const float* __restrict__ W2_b,
    const float* __restrict__ q_w,  const float* __restrict__ q_b,
    const float* __restrict__ W3t, const float* __restrict__ W3_b,
    const float* __restrict__ emb_weight, const int* __restrict__ cue,
    float* __restrict__ y_hat, short* __restrict__ packA)
{
    __shared__ float it[ITEMS][H];        // 8 KB
    __shared__ float contrib[ITEMS][H];   // 8 KB
    __shared__ float red[ITEMS][8];
    __shared__ float alphas[ITEMS];
    __shared__ float sg[H];
    __shared__ float wred[2];

    const int b = blockIdx.x;
    const int j = threadIdx.x;            // 0..127
    const int nbase = b * NODES;

    // --- itemset embeddings: masked gather-mean over this session's 32 nodes
#pragma unroll
    for (int t = 0; t < ITEMS; ++t) {
        const int tg = b * ITEMS + t;
        float acc = 0.f;
#pragma unroll
        for (int p = 0; p < PADLEN; ++p) {
            int s = sequence[tg * PADLEN + p];
            if (s < NODES) acc += node_emb[(nbase + s) * H + j];
        }
        it[t][j] = acc / (float)itemset_len[tg];
    }
    __syncthreads();

    // pre_j = W1_b[j] + W2_b[j] + dot(W1[j,:], v_n)   (v_n = it[15])
    float pre = W1_b[j] + W2_b[j];
#pragma unroll 4
    for (int k = 0; k < H; k += 4) {
        float4 v = *(const float4*)&it[ITEMS - 1][k];
        pre += W1t[(k + 0) * H + j] * v.x + W1t[(k + 1) * H + j] * v.y
             + W1t[(k + 2) * H + j] * v.z + W1t[(k + 3) * H + j] * v.w;
    }

    // h2[t] = dot(W2[j,:], it[t])  for all 16 t, streaming W2t rows (coalesced)
    float h2[ITEMS];
#pragma unroll
    for (int t = 0; t < ITEMS; ++t) h2[t] = 0.f;
    for (int k = 0; k < H; k += 4) {
        float w0 = W2t[(k + 0) * H + j];
        float w1 = W2t[(k + 1) * H + j];
        float w2 = W2t[(k + 2) * H + j];
        float w3 = W2t[(k + 3) * H + j];
#pragma unroll
        for (int t = 0; t < ITEMS; ++t) {
            float4 v = *(const float4*)&it[t][k];
            h2[t] += w0 * v.x + w1 * v.y + w2 * v.z + w3 * v.w;
        }
    }

    // contrib[t][j] = q_w[j] * sigmoid(pre + h2[t])
    const float qwj = q_w[j];
#pragma unroll
    for (int t = 0; t < ITEMS; ++t) {
        float g = 1.f / (1.f + __expf(-(pre + h2[t])));
        contrib[t][j] = qwj * g;
    }
    __syncthreads();

    // block reduce contrib rows -> alphas[t]
    {
        int t = j >> 3, part = j & 7;
        float s = 0.f;
#pragma unroll
        for (int u = 0; u < 16; ++u) s += contrib[t][part * 16 + u];
        red[t][part] = s;
    }
    __syncthreads();
    if (j < ITEMS) {
        float s = q_b[0];
#pragma unroll
        for (int u = 0; u < 8; ++u) s += red[j][u];
        alphas[j] = s;
    }
    __syncthreads();

    // s_g[j] = sum_t alphas[t] * it[t][j]
    float sgj = 0.f;
#pragma unroll
    for (int t = 0; t < ITEMS; ++t) sgj += alphas[t] * it[t][j];
    sg[j] = sgj;
    __syncthreads();

    // s_h[j] = W3_b[j] + dot(W3[j,0:128], v_n) + dot(W3[j,128:256], s_g)
    float sh = W3_b[j];
#pragma unroll 4
    for (int k = 0; k < H; k += 4) {
        float4 v = *(const float4*)&it[ITEMS - 1][k];
        sh += W3t[(k + 0) * H + j] * v.x + W3t[(k + 1) * H + j] * v.y
            + W3t[(k + 2) * H + j] * v.z + W3t[(k + 3) * H + j] * v.w;
    }
#pragma unroll 4
    for (int k = 0; k < H; k += 4) {
        float4 v = *(const float4*)&sg[k];
        sh += W3t[(H + k + 0) * H + j] * v.x + W3t[(H + k + 1) * H + j] * v.y
            + W3t[(H + k + 2) * H + j] * v.z + W3t[(H + k + 3) * H + j] * v.w;
    }

    // write s_h (bf16) in MFMA-fragment-packed layout: k index == j
    {
        const int c = b >> 5, cl = b & 31;
        const int s = j >> 4, hi = (j >> 3) & 1, i = j & 7;
        packA[c * 4096 + s * 512 + hi * 256 + cl * 8 + i] = f2bf(sh);
    }

    // y_hat[b] = dot(s_h, emb_weight[cue[b]])  — full f32
    float prod = sh * emb_weight[(long)cue[b] * H + j];
#pragma unroll
    for (int off = 32; off > 0; off >>= 1) prod += __shfl_down(prod, off);
    if ((j & 63) == 0) wred[j >> 6] = prod;
    __syncthreads();
    if (j == 0) y_hat[b] = wred[0] + wred[1];
}

// ---------------------------------------------------------------------------
// Kernel 2: all_scores = s_h(bf16) @ emb_weight(bf16).T
// R7 geometry/structure. Stores NT (zero-reuse stream, keeps L2 clean for
// packA). emb loads are PLAIN CACHED loads: each 128B emb line is touched by
// 8 separate 16B accesses across 4 instructions -> L1 reuse is essential;
// NT loads defeated it (read amplification). Single variable vs R7.
// ---------------------------------------------------------------------------
__global__ __launch_bounds__(256, 4) void k_scores(
    const float* __restrict__ emb_weight,
    const short* __restrict__ packA,
    float* __restrict__ scores)
{
    // m204 bijective swizzle, nwg = 782, 8 XCDs (round-robin dispatch)
    const int nwg = 782;
    const int xcd = blockIdx.x & 7;
    const int idx = blockIdx.x >> 3;
    const int q = nwg >> 3, r = nwg & 7;          // 97, 6
    const int bid = (xcd < r) ? (xcd * (q + 1) + idx)
                              : (r * (q + 1) + (xcd - r) * q + idx);

    const int wave = threadIdx.x >> 6;
    const int lane = threadIdx.x & 63;
    const int hi = lane >> 5;             // k-group
    const int cl = lane & 31;             // col within tile / row within A
    const int col = bid * 128 + wave * 32 + cl;
    const bool valid = col < VOCAB;       // V%32==0 -> wave-uniform

    // B fragment: lane holds emb[col][s*16 + hi*8 + i], i=0..7, for s=0..7
    short8 bfrag[8];
    if (valid) {
        const float* row = emb_weight + (long)col * H;
#pragma unroll
        for (int s = 0; s < 8; ++s) {
            const f32x4* p = (const f32x4*)(row + s * 16 + hi * 8);
            f32x4 x = p[0];
            f32x4 y = p[1];
            short8 f;
            f[0] = f2bf(x[0]); f[1] = f2bf(x[1]); f[2] = f2bf(x[2]); f[3] = f2bf(x[3]);
            f[4] = f2bf(y[0]); f[5] = f2bf(y[1]); f[6] = f2bf(y[2]); f[7] = f2bf(y[3]);
            bfrag[s] = f;
        }
    } else {
#pragma unroll
        for (int s = 0; s < 8; ++s) {
            short8 z;
#pragma unroll
            for (int i = 0; i < 8; ++i) z[i] = 0;
            bfrag[s] = z;
        }
    }

    for (int c = 0; c < NCHUNK; ++c) {
        const short* ap = packA + c * 4096 + hi * 256 + cl * 8;
        short8 a[8];
#pragma unroll
        for (int s = 0; s < 8; ++s) a[s] = *(const short8*)(ap + s * 512);
        f32x16 acc;
#pragma unroll
        for (int r2 = 0; r2 < 16; ++r2) acc[r2] = 0.f;
#pragma unroll
        for (int s = 0; s < 8; ++s)
            acc = __builtin_amdgcn_mfma_f32_32x32x16_bf16(a[s], bfrag[s], acc, 0, 0, 0);
        if (valid) {
            const int M0 = c * 32;
#pragma unroll
            for (int r2 = 0; r2 < 16; ++r2) {
                int rowm = (r2 & 3) + 8 * (r2 >> 2) + 4 * hi;
                __builtin_nontemporal_store(acc[r2],
                    &scores[(long)(M0 + rowm) * VOCAB + col]);
            }
        }
    }
}

// ---------------------------------------------------------------------------
extern "C" void kernel_launch(void* const* d_in, const int* in_sizes, int n_in,
                              void* d_out, int out_size, void* d_ws, size_t ws_size,
                              hipStream_t stream) {
    const float* node_emb   = (const float*)d_in[0];
    const float* emb_w      = (const float*)d_in[1];
    const float* W1_w       = (const float*)d_in[2];
    const float* W1_b       = (const float*)d_in[3];
    const float* W2_w       = (const float*)d_in[4];
    const float* W2_b       = (const float*)d_in[5];
    const float* q_w        = (const float*)d_in[6];
    const float* q_b        = (const float*)d_in[7];
    const float* W3_w       = (const float*)d_in[8];
    const float* W3_b       = (const float*)d_in[9];
    // d_in[10] batch (= repeat(arange(B),32)), d_in[13] sequence_len (=16): structure hardcoded
    const int* sequence     = (const int*)d_in[11];
    const int* itemset_len  = (const int*)d_in[12];
    const int* cue          = (const int*)d_in[14];

    float* out    = (float*)d_out;
    float* y_hat  = out;                   // [B]
    float* scores = out + B_SESS;          // [B][V]

    short* packA = (short*)d_ws;                            // 256 KB
    float* W1t   = (float*)((char*)d_ws + (256 << 10));     // 64 KB
    float* W2t   = W1t + H * H;                             // 64 KB
    float* W3t   = W2t + H * H;                             // 128 KB

    k_transpose<<<64, 256, 0, stream>>>(W1_w, W2_w, W3_w, W1t, W2t, W3t);
    k_session<<<B_SESS, H, 0, stream>>>(node_emb, sequence, itemset_len,
                                        W1t, W1_b, W2t, W2_b,
                                        q_w, q_b, W3t, W3_b, emb_w, cue,
                                        y_hat, packA);
    const int nblk = (VOCAB + 127) / 128;  // 782
    k_scores<<<nblk, 256, 0, stream>>>(emb_w, packA, scores);
}